// Round 2
// baseline (34.812 us; speedup 1.0000x reference)
//
#include <hip/hip_runtime.h>

// RegularizationLoss: out = mean_b( ||M1 M1^T - I||_F^2 + ||M2 M2^T - I||_F^2 )
// input: (2000000, 6, 3) f32 = 4,000,000 consecutive 3x3 matrices.
// Loss = (1/2e6) * sum over ALL 4M matrices M of ||M M^T - I||_F^2
// (batch substructure is irrelevant to the sum).
// Memory-bound streaming reduction: 144 MB read -> scalar.

#define NBLK 977   // threads = 250,112; 500,000 quads -> ~2.0 iters/thread (balanced)
#define NTHR 256

__global__ __launch_bounds__(NTHR) void reg_loss_partial(
    const float4* __restrict__ in4, float* __restrict__ partial, int nquads) {
    const int tid = blockIdx.x * NTHR + threadIdx.x;
    const int stride = NBLK * NTHR;
    float acc = 0.0f;

    for (int q = tid; q < nquads; q += stride) {
        // one quad = 72 floats = 8 consecutive 3x3 matrices = 18 float4 (288 B)
        float4 v[18];
        #pragma unroll
        for (int k = 0; k < 18; ++k) v[k] = in4[(size_t)q * 18 + k];

        float m[72];
        #pragma unroll
        for (int k = 0; k < 18; ++k) {
            m[4 * k + 0] = v[k].x;
            m[4 * k + 1] = v[k].y;
            m[4 * k + 2] = v[k].z;
            m[4 * k + 3] = v[k].w;
        }

        #pragma unroll
        for (int h = 0; h < 8; ++h) {
            const float* M = m + h * 9;   // rows: M[0..2], M[3..5], M[6..8]
            // A = M M^T - I is symmetric: diag once, off-diag x2
            float a00 = M[0]*M[0] + M[1]*M[1] + M[2]*M[2] - 1.0f;
            float a11 = M[3]*M[3] + M[4]*M[4] + M[5]*M[5] - 1.0f;
            float a22 = M[6]*M[6] + M[7]*M[7] + M[8]*M[8] - 1.0f;
            float a01 = M[0]*M[3] + M[1]*M[4] + M[2]*M[5];
            float a02 = M[0]*M[6] + M[1]*M[7] + M[2]*M[8];
            float a12 = M[3]*M[6] + M[4]*M[7] + M[5]*M[8];
            acc += a00*a00 + a11*a11 + a22*a22
                 + 2.0f * (a01*a01 + a02*a02 + a12*a12);
        }
    }

    // wave64 reduction
    #pragma unroll
    for (int off = 32; off > 0; off >>= 1) acc += __shfl_down(acc, off, 64);

    __shared__ float wsum[NTHR / 64];
    const int lane = threadIdx.x & 63;
    const int wid  = threadIdx.x >> 6;
    if (lane == 0) wsum[wid] = acc;
    __syncthreads();
    if (threadIdx.x == 0) {
        float s = 0.0f;
        #pragma unroll
        for (int w = 0; w < NTHR / 64; ++w) s += wsum[w];
        partial[blockIdx.x] = s;
    }
}

__global__ __launch_bounds__(256) void reg_loss_final(
    const float* __restrict__ partial, float* __restrict__ out, int nb, float invN) {
    float acc = 0.0f;
    for (int i = threadIdx.x; i < nb; i += 256) acc += partial[i];
    #pragma unroll
    for (int off = 32; off > 0; off >>= 1) acc += __shfl_down(acc, off, 64);

    __shared__ float wsum[4];
    const int lane = threadIdx.x & 63;
    const int wid  = threadIdx.x >> 6;
    if (lane == 0) wsum[wid] = acc;
    __syncthreads();
    if (threadIdx.x == 0) {
        out[0] = (wsum[0] + wsum[1] + wsum[2] + wsum[3]) * invN;
    }
}

extern "C" void kernel_launch(void* const* d_in, const int* in_sizes, int n_in,
                              void* d_out, int out_size, void* d_ws, size_t ws_size,
                              hipStream_t stream) {
    const float* in = (const float*)d_in[0];
    float* out = (float*)d_out;
    float* partial = (float*)d_ws;  // NBLK floats of scratch

    const int total_floats = in_sizes[0];      // 36,000,000
    const int nbatch = total_floats / 18;      // 2,000,000
    const int nquads = total_floats / 72;      // 500,000 (8 matrices each)

    reg_loss_partial<<<NBLK, NTHR, 0, stream>>>((const float4*)in, partial, nquads);
    reg_loss_final<<<1, 256, 0, stream>>>(partial, out, NBLK, 1.0f / (float)nbatch);
}

// Round 3
// 29.361 us; speedup vs baseline: 1.1857x; 1.1857x over previous
//
#include <hip/hip_runtime.h>

// RegularizationLoss: out = (1/2e6) * sum over 4M consecutive 3x3 matrices M
// of ||M M^T - I||_F^2.  Input (2000000,6,3) f32 = 144 MB. Memory-bound.
//
// Strategy: perfectly coalesced unit-stride float4 loads -> LDS tile ->
// per-thread matrix compute from LDS (9*t float offsets: odd stride, 32 banks,
// free 2-way wave64 aliasing).

#define NTHR 256
#define NBLK 977          // 3907 tiles / 977 blocks = 3.999 tiles/block
#define TILE_M 1024       // matrices per tile
#define TILE_F4 2304      // float4 per tile (1024*9/4)
#define TILE_FLOATS 9216  // 36 KB LDS -> 4 blocks/CU

__global__ __launch_bounds__(NTHR) void reg_loss_partial(
    const float4* __restrict__ in4, float* __restrict__ partial,
    int ntiles, int total_f4, int total_m) {
    __shared__ float lds[TILE_FLOATS];
    const int t = threadIdx.x;
    float acc = 0.0f;

    for (int T = blockIdx.x; T < ntiles; T += NBLK) {
        const long long base4 = (long long)T * TILE_F4;
        __syncthreads();  // LDS reuse guard (prev iter reads done)
        #pragma unroll
        for (int k = 0; k < 9; ++k) {
            const int i4 = t + NTHR * k;           // unit stride across wave
            const long long g4 = base4 + i4;
            if (g4 < (long long)total_f4) {
                *(float4*)&lds[4 * i4] = in4[g4];
            }
        }
        __syncthreads();

        const int baseM = T * TILE_M;
        #pragma unroll
        for (int k = 0; k < 4; ++k) {
            const int ml = t + NTHR * k;
            if (baseM + ml < total_m) {
                const float* M = &lds[9 * ml];
                float a00 = M[0]*M[0] + M[1]*M[1] + M[2]*M[2] - 1.0f;
                float a11 = M[3]*M[3] + M[4]*M[4] + M[5]*M[5] - 1.0f;
                float a22 = M[6]*M[6] + M[7]*M[7] + M[8]*M[8] - 1.0f;
                float a01 = M[0]*M[3] + M[1]*M[4] + M[2]*M[5];
                float a02 = M[0]*M[6] + M[1]*M[7] + M[2]*M[8];
                float a12 = M[3]*M[6] + M[4]*M[7] + M[5]*M[8];
                acc += a00*a00 + a11*a11 + a22*a22
                     + 2.0f * (a01*a01 + a02*a02 + a12*a12);
            }
        }
    }

    // wave64 reduction
    #pragma unroll
    for (int off = 32; off > 0; off >>= 1) acc += __shfl_down(acc, off, 64);

    __shared__ float wsum[NTHR / 64];
    const int lane = t & 63;
    const int wid  = t >> 6;
    if (lane == 0) wsum[wid] = acc;
    __syncthreads();
    if (t == 0) {
        float s = 0.0f;
        #pragma unroll
        for (int w = 0; w < NTHR / 64; ++w) s += wsum[w];
        partial[blockIdx.x] = s;
    }
}

__global__ __launch_bounds__(256) void reg_loss_final(
    const float* __restrict__ partial, float* __restrict__ out, int nb, float invN) {
    float acc = 0.0f;
    for (int i = threadIdx.x; i < nb; i += 256) acc += partial[i];
    #pragma unroll
    for (int off = 32; off > 0; off >>= 1) acc += __shfl_down(acc, off, 64);

    __shared__ float wsum[4];
    const int lane = threadIdx.x & 63;
    const int wid  = threadIdx.x >> 6;
    if (lane == 0) wsum[wid] = acc;
    __syncthreads();
    if (threadIdx.x == 0) {
        out[0] = (wsum[0] + wsum[1] + wsum[2] + wsum[3]) * invN;
    }
}

extern "C" void kernel_launch(void* const* d_in, const int* in_sizes, int n_in,
                              void* d_out, int out_size, void* d_ws, size_t ws_size,
                              hipStream_t stream) {
    const float* in = (const float*)d_in[0];
    float* out = (float*)d_out;
    float* partial = (float*)d_ws;  // NBLK floats of scratch

    const int total_floats = in_sizes[0];          // 36,000,000
    const int total_m = total_floats / 9;          // 4,000,000 matrices
    const int total_f4 = total_floats / 4;         // 9,000,000 float4
    const int nbatch = total_floats / 18;          // 2,000,000
    const int ntiles = (total_m + TILE_M - 1) / TILE_M;  // 3907

    reg_loss_partial<<<NBLK, NTHR, 0, stream>>>((const float4*)in, partial,
                                                ntiles, total_f4, total_m);
    reg_loss_final<<<1, 256, 0, stream>>>(partial, out, NBLK, 1.0f / (float)nbatch);
}